// Round 12
// baseline (3058.353 us; speedup 1.0000x reference)
//
#include <hip/hip_runtime.h>
#include <hip/hip_bf16.h>
#include <math.h>

#define N_NODES 100000
#define N_EDGES 1600000
#define ET (N_EDGES + N_NODES)   // edges + self-loops
#define N_GRAPHS 512
#define NEG_SLOPE 0.2f
#define GRID 2048                // all blocks co-resident: 8/CU x 256 CU

// ---- bucketed CSR build params ----
#define BSH 8                                 // 256 nodes per bucket
#define NBUCK ((N_NODES + 255) / 256)         // 391
#define BCAP 5120                             // per-bucket capacity
#define ABLK 1024                             // binA sub-grid (blocks 0..1023)
#define CHUNK ((ET + ABLK - 1) / ABLK)        // 1661 edges per binA block

__device__ __forceinline__ void atomAddF(float* p, float v) { unsafeAtomicAdd(p, v); }
__device__ __forceinline__ float lrelu(float v) { return v >= 0.f ? v : NEG_SLOPE * v; }

__device__ __forceinline__ unsigned short f2bf(float f) {
    unsigned int u = __float_as_uint(f);
    u += 0x7FFFu + ((u >> 16) & 1u);
    return (unsigned short)(u >> 16);
}
__device__ __forceinline__ float bf2f(unsigned short s) { return __uint_as_float(((unsigned int)s) << 16); }
__device__ __forceinline__ float bflo(unsigned int p) { return __uint_as_float(p << 16); }
__device__ __forceinline__ float bfhi(unsigned int p) { return __uint_as_float(p & 0xFFFF0000u); }

// ---- device-global sync state (zero-init at load; reset at kernel end) ----
__device__ unsigned g_bar[3];
__device__ unsigned g_flag;
__device__ unsigned g_done;

__device__ __forceinline__ void gridbar(unsigned* ctr) {
    __syncthreads();
    if (threadIdx.x == 0) {
        __threadfence();                 // release: publish this block's writes
        atomicAdd(ctr, 1u);
        while (__hip_atomic_load(ctr, __ATOMIC_ACQUIRE, __HIP_MEMORY_SCOPE_AGENT) < GRID)
            __builtin_amdgcn_s_sleep(10);
        __threadfence();                 // acquire: see all blocks' writes
    }
    __syncthreads();
}

// =============== single fused kernel: CSR + conv1 + conv2 + pool ==========
__global__ __launch_bounds__(256, 8) void k_all(
    const int* __restrict__ ei, const int* __restrict__ batch,
    const float* __restrict__ x, const float* __restrict__ W1,
    const float* __restrict__ as1, const float* __restrict__ ad1,
    const float* __restrict__ b1,
    const float* __restrict__ W2, const float* __restrict__ as2,
    const float* __restrict__ ad2, const float* __restrict__ b2,
    const float* __restrict__ Wg, const float* __restrict__ bg,
    uint2* __restrict__ gbuf, int* __restrict__ bcur,
    int* __restrict__ rowptr, int* __restrict__ ecol,
    unsigned short* __restrict__ h1p, unsigned short* __restrict__ a1sh,
    float* __restrict__ a1d, float* __restrict__ wv,
    float2* __restrict__ sg2, float* __restrict__ a2dv,
    float* __restrict__ out)
{
    __shared__ __align__(16) char smem[19552];   // union of all phase needs
    const int t = threadIdx.x;
    const int blk = blockIdx.x;

    // ---------------- P0: init tasks (tiny, on dedicated blocks) ----------
    if (blk == 0) {
        for (int i = t; i < NBUCK; i += 256) atomicExch(&bcur[i], 0);
        __syncthreads();
        if (t == 0) { __threadfence(); atomicExch(&g_flag, 1u); }
    } else if (blk == 1) {
        if (t < 192) {
            int c = t & 63, which = t >> 6;
            const float* v = (which == 0) ? Wg : ((which == 1) ? as2 : ad2);
            float s = 0.f;
            #pragma unroll
            for (int k = 0; k < 128; ++k) s += W2[c * 128 + k] * v[k];
            wv[which * 64 + c] = s;
        } else if (t == 192) {
            float s = 0.f;
            #pragma unroll
            for (int k = 0; k < 128; ++k) s += b2[k] * Wg[k];
            wv[192] = s;
        }
    } else if (blk == 2 || blk == 3) {
        int i = (blk - 2) * 256 + t;
        if (i < N_GRAPHS) atomicExch((unsigned*)&out[i], __float_as_uint(bg[0]));
    }

    // ---------------- P1: binA (blocks 0..ABLK-1) -------------------------
    if (blk < ABLK) {
        uint2* pairs = (uint2*)smem;                       // CHUNK x 8 B
        int* hist  = (int*)(smem + CHUNK * 8);             // NBUCK
        int* excl  = hist + NBUCK;
        int* gbase = excl + NBUCK;
        int* cnt2  = gbase + NBUCK;
        const long e0 = (long)blk * CHUNK;
        const int  n  = (int)((e0 + CHUNK <= ET) ? CHUNK : (ET - e0));
        for (int i = t; i < NBUCK; i += 256) { hist[i] = 0; cnt2[i] = 0; }
        __syncthreads();
        for (int i = t; i < n; i += 256) {
            long e = e0 + i;
            int dst = (e < N_EDGES) ? ei[N_EDGES + e] : (int)(e - N_EDGES);
            atomicAdd(&hist[dst >> BSH], 1);
        }
        __syncthreads();
        if (t == 0) {
            int acc = 0;
            for (int b = 0; b < NBUCK; ++b) { excl[b] = acc; acc += hist[b]; }
        }
        __syncthreads();
        for (int i = t; i < n; i += 256) {
            long e = e0 + i;
            int src, dst;
            if (e < N_EDGES) { src = ei[e]; dst = ei[N_EDGES + e]; }
            else             { src = dst = (int)(e - N_EDGES); }
            int b = dst >> BSH;
            int pos = excl[b] + atomicAdd(&cnt2[b], 1);
            pairs[pos] = make_uint2((unsigned)src, (unsigned)dst);
        }
        // wait for bcur zeroing before global reservation
        if (t == 0) {
            while (__hip_atomic_load(&g_flag, __ATOMIC_ACQUIRE, __HIP_MEMORY_SCOPE_AGENT) == 0u)
                __builtin_amdgcn_s_sleep(2);
        }
        __syncthreads();
        for (int b = t; b < NBUCK; b += 256)
            gbase[b] = hist[b] ? atomicAdd(&bcur[b], hist[b]) : 0;
        __syncthreads();
        for (int i = t; i < n; i += 256) {
            uint2 pr = pairs[i];
            int b = (int)(pr.y >> BSH);
            gbuf[(long)b * BCAP + gbase[b] + (i - excl[b])] = pr;
        }
    }

    gridbar(&g_bar[0]);

    // ---------------- P2: binB (blocks < NBUCK) | feat1 (rest) ------------
    if (blk < NBUCK) {
        int* hist = (int*)smem;          // 256
        int* excl = hist + 256;
        int* cnt2 = excl + 256;
        int* red  = cnt2 + 256;
        const int b = blk;
        const int cnt  = bcur[b];
        const int d0 = b << BSH;
        const int nloc = (N_NODES - d0 < 256) ? (N_NODES - d0) : 256;

        int partial = 0;
        for (int i = t; i < b; i += 256) partial += bcur[i];
        red[t] = partial;
        __syncthreads();
        for (int off = 128; off > 0; off >>= 1) {
            if (t < off) red[t] += red[t + off];
            __syncthreads();
        }
        const int base = red[0];

        if (t < nloc) { hist[t] = 0; cnt2[t] = 0; }
        __syncthreads();
        const uint2* eb = gbuf + (long)b * BCAP;
        for (int i = t; i < cnt; i += 256) atomicAdd(&hist[(int)eb[i].y - d0], 1);
        __syncthreads();
        if (t == 0) {
            int acc = 0;
            for (int k = 0; k < nloc; ++k) { excl[k] = acc; acc += hist[k]; }
        }
        __syncthreads();
        if (t < nloc) rowptr[d0 + t] = base + excl[t];
        if (b == NBUCK - 1 && t == 0) rowptr[N_NODES] = base + cnt;   // == ET
        for (int i = t; i < cnt; i += 256) {
            uint2 pr = eb[i];
            int dl = (int)pr.y - d0;
            int slot = excl[dl] + atomicAdd(&cnt2[dl], 1);
            ecol[base + slot] = (int)pr.x;
        }
    } else {
        float (*xs)[76] = (float (*)[76])smem;
        const int g = t >> 6;
        const int c = t & 63;
        const int vb = blk - NBUCK;
        const int fstride = GRID - NBUCK;
        for (int nb = vb; nb < N_NODES / 4; nb += fstride) {
            const int n = nb * 4 + g;
            const float* xr = x + (long)n * 75;
            xs[g][c] = xr[c];
            if (c < 11) xs[g][64 + c] = xr[64 + c];
            __syncthreads();
            float h = 0.f;
            #pragma unroll
            for (int k = 0; k < 75; ++k) h += xs[g][k] * W1[k * 64 + c];
            h1p[(long)n * 64 + c] = f2bf(h);
            const int head = c >> 3, lane = c & 7;
            float vs = h * as1[c];
            float vd = h * ad1[c];
            #pragma unroll
            for (int off = 1; off < 8; off <<= 1) {
                vs += __shfl_xor(vs, off, 64);
                vd += __shfl_xor(vd, off, 64);
            }
            if (lane == 0) { a1sh[n * 8 + head] = f2bf(vs); a1d[n * 8 + head] = vd; }
            __syncthreads();
        }
    }

    gridbar(&g_bar[1]);

    // ---------------- P3: gat1 (all blocks) -------------------------------
    {
        const int slot = t >> 6;
        const int lane = t & 63;
        const int g = lane >> 3;
        const int l = lane & 7;
        for (int base = blk * 4; base < N_NODES; base += GRID * 4) {
            const int dst = base + slot;
            const int beg = rowptr[dst], end = rowptr[dst + 1];
            const float adh = a1d[(long)dst * 8 + l];

            float acc[8] = {0.f,0.f,0.f,0.f,0.f,0.f,0.f,0.f};
            float den = 0.f;

            int j = beg + g;
            bool v = (j < end);
            int s = v ? ecol[j] : 0;
            unsigned short ab = a1sh[(long)s * 8 + l];
            uint4 pv = *(const uint4*)(h1p + (long)s * 64 + l * 8);

            for (int j0 = beg; j0 < end; j0 += 8) {
                int jn = j + 8;
                bool vn = (jn < end);
                int sn = vn ? ecol[jn] : 0;
                unsigned short abn = a1sh[(long)sn * 8 + l];
                uint4 pvn = *(const uint4*)(h1p + (long)sn * 64 + l * 8);
                float ee = v ? __expf(lrelu(bf2f(ab) + adh)) : 0.f;
                den += ee;
                acc[0] += ee * bflo(pv.x); acc[1] += ee * bfhi(pv.x);
                acc[2] += ee * bflo(pv.y); acc[3] += ee * bfhi(pv.y);
                acc[4] += ee * bflo(pv.z); acc[5] += ee * bfhi(pv.z);
                acc[6] += ee * bflo(pv.w); acc[7] += ee * bfhi(pv.w);
                j = jn; v = vn; s = sn; ab = abn; pv = pvn;
            }
            #pragma unroll
            for (int off = 8; off <= 32; off <<= 1) {
                den += __shfl_xor(den, off, 64);
                #pragma unroll
                for (int k = 0; k < 8; ++k) acc[k] += __shfl_xor(acc[k], off, 64);
            }

            if (g == 0) {
                const float inv = 1.f / den;
                float pg = 0.f, ps = 0.f, pd = 0.f;
                #pragma unroll
                for (int k = 0; k < 8; ++k) {
                    float vv = acc[k] * inv + b1[l * 8 + k];
                    vv = vv > 0.f ? vv : (__expf(vv) - 1.f);
                    pg += vv * wv[l * 8 + k];
                    ps += vv * wv[64 + l * 8 + k];
                    pd += vv * wv[128 + l * 8 + k];
                }
                #pragma unroll
                for (int off = 1; off < 8; off <<= 1) {
                    pg += __shfl_xor(pg, off, 64);
                    ps += __shfl_xor(ps, off, 64);
                    pd += __shfl_xor(pd, off, 64);
                }
                if (l == 0) { sg2[dst] = make_float2(ps, pg); a2dv[dst] = pd; }
            }
        }
    }

    gridbar(&g_bar[2]);

    // ---------------- P4: gat2 + pool + linear ----------------------------
    {
        const int lane = t & 63;
        const int sl = lane & 15;
        const int sgid = ((blk * 256 + t) >> 4);
        const int NS = GRID * 16;
        const int per = (N_NODES + NS - 1) / NS;
        const int n0 = sgid * per;
        const int n1 = min(n0 + per, N_NODES);
        const float bc = wv[192];

        float accg = 0.f;
        int curg = -1;
        for (int n = n0; n < n1; ++n) {
            const int beg = rowptr[n], end = rowptr[n + 1];
            const float adv = a2dv[n];
            float num = 0.f, den = 0.f;
            for (int j = beg + sl; j < end; j += 16) {
                int s = ecol[j];
                float2 v = sg2[s];
                float ee = __expf(lrelu(v.x + adv));
                den += ee;
                num += ee * v.y;
            }
            #pragma unroll
            for (int off = 1; off < 16; off <<= 1) {
                den += __shfl_xor(den, off, 64);
                num += __shfl_xor(num, off, 64);
            }
            if (sl == 0) {
                int gr = batch[n];
                if (gr != curg) {
                    if (curg >= 0) atomAddF(out + curg, accg);
                    curg = gr; accg = 0.f;
                }
                accg += num / den + bc;
            }
        }
        if (sl == 0 && curg >= 0) atomAddF(out + curg, accg);
    }

    // ---------------- reset sync state for next (replayed) call -----------
    __syncthreads();
    if (t == 0) {
        unsigned d = atomicAdd(&g_done, 1u);
        if (d == GRID - 1) {
            atomicExch(&g_bar[0], 0u);
            atomicExch(&g_bar[1], 0u);
            atomicExch(&g_bar[2], 0u);
            atomicExch(&g_flag, 0u);
            atomicExch(&g_done, 0u);
        }
    }
}

extern "C" void kernel_launch(void* const* d_in, const int* in_sizes, int n_in,
                              void* d_out, int out_size, void* d_ws, size_t ws_size,
                              hipStream_t stream) {
    (void)in_sizes; (void)n_in; (void)out_size; (void)ws_size;
    const float* x     = (const float*)d_in[0];
    const int*   ei    = (const int*)d_in[1];
    const int*   batch = (const int*)d_in[2];
    const float* W1    = (const float*)d_in[3];
    const float* as1   = (const float*)d_in[4];
    const float* ad1   = (const float*)d_in[5];
    const float* b1    = (const float*)d_in[6];
    const float* W2    = (const float*)d_in[7];
    const float* as2   = (const float*)d_in[8];
    const float* ad2   = (const float*)d_in[9];
    const float* b2    = (const float*)d_in[10];
    const float* Wg    = (const float*)d_in[11];
    const float* bg    = (const float*)d_in[12];
    float* out = (float*)d_out;

    // ---- workspace layout (16-B aligned chunks; total ~45 MB) ----
    const long N = N_NODES;
    char* p = (char*)d_ws;
    int* rowptr = (int*)p;              p += (N + 4)        * sizeof(int);
    int* bcur   = (int*)p;              p += 512            * sizeof(int);
    int* ecol   = (int*)p;              p += (long)ET       * sizeof(int);
    uint2* gbuf = (uint2*)p;            p += (long)NBUCK * BCAP * sizeof(uint2);
    unsigned short* h1p  = (unsigned short*)p; p += N * 64  * sizeof(unsigned short);
    unsigned short* a1sh = (unsigned short*)p; p += N * 8   * sizeof(unsigned short);
    float* a1d  = (float*)p;            p += N * 8          * sizeof(float);
    float2* sg2 = (float2*)p;           p += N              * sizeof(float2);
    float* a2dv = (float*)p;            p += N              * sizeof(float);
    float* wv   = (float*)p;            p += 256            * sizeof(float);

    // single fused launch: CSR build + conv1 + conv2 + pool + linear
    k_all<<<GRID, 256, 0, stream>>>(ei, batch, x, W1, as1, ad1, b1,
                                    W2, as2, ad2, b2, Wg, bg,
                                    gbuf, bcur, rowptr, ecol,
                                    h1p, a1sh, a1d, wv, sg2, a2dv, out);
}

// Round 13
// 281.205 us; speedup vs baseline: 10.8759x; 10.8759x over previous
//
#include <hip/hip_runtime.h>
#include <hip/hip_bf16.h>
#include <math.h>

#define N_NODES 100000
#define N_EDGES 1600000
#define ET (N_EDGES + N_NODES)   // edges + self-loops
#define N_GRAPHS 512
#define NEG_SLOPE 0.2f
#define G2_BLOCKS 1280           // persistent k_gat2 grid

// ---- bucketed CSR params ----
#define BSH 7                                 // 128 nodes per bucket
#define NDB 128                               // dsts per bucket
#define NBUCK ((N_NODES + NDB - 1) / NDB)     // 782
#define BCAP 2560                             // bucket capacity (mean 2174, +8 sigma)
#define ABLK 512                              // binA sub-grid
#define CHUNK ((ET + ABLK - 1) / ABLK)        // 3321 edges per binA block
#define F1_OFF (ABLK + 3)                     // feat1 blocks start here in k_pre
#define PRE_GRID (F1_OFF + 1536)              // 2051

__device__ __forceinline__ void atomAddF(float* p, float v) { unsafeAtomicAdd(p, v); }
__device__ __forceinline__ float lrelu(float v) { return v >= 0.f ? v : NEG_SLOPE * v; }

__device__ __forceinline__ unsigned short f2bf(float f) {
    unsigned int u = __float_as_uint(f);
    u += 0x7FFFu + ((u >> 16) & 1u);
    return (unsigned short)(u >> 16);
}
__device__ __forceinline__ float bf2f(unsigned short s) { return __uint_as_float(((unsigned int)s) << 16); }
__device__ __forceinline__ float bflo(unsigned int p) { return __uint_as_float(p << 16); }
__device__ __forceinline__ float bfhi(unsigned int p) { return __uint_as_float(p & 0xFFFF0000u); }

// ============ Launch 1: binA (blocks 0..ABLK-1) + wv/init + feat1 =========
__global__ __launch_bounds__(256) void k_pre(
    const int* __restrict__ ei, uint2* __restrict__ gbuf, int* __restrict__ bcur,
    const float* __restrict__ x, const float* __restrict__ W1,
    const float* __restrict__ as1, const float* __restrict__ ad1,
    const float* __restrict__ W2, const float* __restrict__ as2,
    const float* __restrict__ ad2, const float* __restrict__ Wg,
    const float* __restrict__ b2, const float* __restrict__ bg,
    unsigned short* __restrict__ h1p, unsigned short* __restrict__ a1sh,
    float* __restrict__ a1d, float* __restrict__ wv, float* __restrict__ out)
{
    __shared__ __align__(16) char smem[CHUNK * 8 + NBUCK * 16 + 1024];  // 40104 B
    const int t = threadIdx.x;
    const int blk = blockIdx.x;

    if (blk >= ABLK && blk < F1_OFF) {
        // ---- misc: wv precompute / out init ----
        const int bb = blk - ABLK;
        if (bb == 0) {
            if (t < 192) {
                int c = t & 63, which = t >> 6;
                const float* v = (which == 0) ? Wg : ((which == 1) ? as2 : ad2);
                float s = 0.f;
                #pragma unroll
                for (int k = 0; k < 128; ++k) s += W2[c * 128 + k] * v[k];
                wv[which * 64 + c] = s;
            } else if (t == 192) {
                float s = 0.f;
                #pragma unroll
                for (int k = 0; k < 128; ++k) s += b2[k] * Wg[k];
                wv[192] = s;
            }
        } else {
            int i = (bb - 1) * 256 + t;
            if (i < N_GRAPHS) out[i] = bg[0];
        }
        return;
    }

    if (blk >= F1_OFF) {
        // ---- feat1 (persistent over node groups) ----
        float (*xs)[76] = (float (*)[76])smem;
        const int g = t >> 6;
        const int c = t & 63;
        const int vb = blk - F1_OFF;
        const int fstride = PRE_GRID - F1_OFF;
        for (int nb = vb; nb < N_NODES / 4; nb += fstride) {
            const int n = nb * 4 + g;
            const float* xr = x + (long)n * 75;
            xs[g][c] = xr[c];
            if (c < 11) xs[g][64 + c] = xr[64 + c];
            __syncthreads();
            float h = 0.f;
            #pragma unroll
            for (int k = 0; k < 75; ++k) h += xs[g][k] * W1[k * 64 + c];
            h1p[(long)n * 64 + c] = f2bf(h);
            const int head = c >> 3, lane = c & 7;
            float vs = h * as1[c];
            float vd = h * ad1[c];
            #pragma unroll
            for (int off = 1; off < 8; off <<= 1) {
                vs += __shfl_xor(vs, off, 64);
                vd += __shfl_xor(vd, off, 64);
            }
            if (lane == 0) { a1sh[n * 8 + head] = f2bf(vs); a1d[n * 8 + head] = vd; }
            __syncthreads();
        }
        return;
    }

    // ---- binA: per-chunk LDS counting sort by bucket ----
    uint2* pairs = (uint2*)smem;                       // CHUNK x 8 B
    int* hist  = (int*)(smem + CHUNK * 8);             // NBUCK
    int* excl  = hist + NBUCK;
    int* gbase = excl + NBUCK;
    int* cnt2  = gbase + NBUCK;
    int* red   = cnt2 + NBUCK;                         // 256
    const long e0 = (long)blk * CHUNK;
    const int  n  = (int)((e0 + CHUNK <= ET) ? CHUNK : (ET - e0));
    for (int i = t; i < NBUCK; i += 256) { hist[i] = 0; cnt2[i] = 0; }
    __syncthreads();
    for (int i = t; i < n; i += 256) {
        long e = e0 + i;
        int dst = (e < N_EDGES) ? ei[N_EDGES + e] : (int)(e - N_EDGES);
        atomicAdd(&hist[dst >> BSH], 1);
    }
    __syncthreads();
    // two-level parallel exclusive scan of hist[NBUCK] (4 buckets/thread)
    {
        int lk[4]; int s = 0;
        #pragma unroll
        for (int k = 0; k < 4; ++k) {
            int idx = t * 4 + k;
            int v = (idx < NBUCK) ? hist[idx] : 0;
            lk[k] = s; s += v;
        }
        red[t] = s;
        __syncthreads();
        for (int off = 1; off < 256; off <<= 1) {
            int a = (t >= off) ? red[t - off] : 0;
            __syncthreads();
            red[t] += a;
            __syncthreads();
        }
        int p = red[t] - s;   // exclusive prefix of this thread's chunk
        #pragma unroll
        for (int k = 0; k < 4; ++k) {
            int idx = t * 4 + k;
            if (idx < NBUCK) excl[idx] = p + lk[k];
        }
    }
    __syncthreads();
    for (int i = t; i < n; i += 256) {
        long e = e0 + i;
        int src, dst;
        if (e < N_EDGES) { src = ei[e]; dst = ei[N_EDGES + e]; }
        else             { src = dst = (int)(e - N_EDGES); }
        int b = dst >> BSH;
        int pos = excl[b] + atomicAdd(&cnt2[b], 1);
        pairs[pos] = make_uint2((unsigned)src, (unsigned)dst);
    }
    __syncthreads();
    for (int b = t; b < NBUCK; b += 256)
        gbase[b] = hist[b] ? atomicAdd(&bcur[b], hist[b]) : 0;
    __syncthreads();
    for (int i = t; i < n; i += 256) {
        uint2 pr = pairs[i];
        int b = (int)(pr.y >> BSH);
        gbuf[(long)b * BCAP + gbase[b] + (i - excl[b])] = pr;
    }
}

// ====== Launch 2: fused binB + gat1.  Block = one 128-dst bucket. =========
__global__ __launch_bounds__(512) void k_gat1(
    const uint2* __restrict__ gbuf, const int* __restrict__ bcur,
    int* __restrict__ rowptr, int* __restrict__ ecol,
    const unsigned short* __restrict__ a1sh, const float* __restrict__ a1d,
    const unsigned short* __restrict__ h1p, const float* __restrict__ bias1,
    const float* __restrict__ wv,
    float2* __restrict__ sg2, float* __restrict__ a2dv)
{
    __shared__ int lds_ecol[BCAP];
    __shared__ int hist[NDB], excl[NDB + 1], cnt2[NDB];
    __shared__ int red[512];
    const int t = threadIdx.x;
    const int b = blockIdx.x;
    const int d0 = b << BSH;
    const int nloc = (N_NODES - d0 < NDB) ? (N_NODES - d0) : NDB;
    const int cnt = bcur[b];

    // ---- base = sum of bcur[0..b) (tree reduce over strided partials) ----
    int partial = 0;
    for (int i = t; i < b; i += 512) partial += bcur[i];
    red[t] = partial;
    __syncthreads();
    for (int off = 256; off > 0; off >>= 1) {
        if (t < off) red[t] += red[t + off];
        __syncthreads();
    }
    const int base = red[0];
    __syncthreads();

    // ---- local histogram over 128 dsts ----
    if (t < NDB) { hist[t] = 0; cnt2[t] = 0; }
    __syncthreads();
    const uint2* eb = gbuf + (long)b * BCAP;
    for (int i = t; i < cnt; i += 512) atomicAdd(&hist[(int)eb[i].y - d0], 1);
    __syncthreads();
    // ---- parallel exclusive scan of hist[128] ----
    {
        int v = (t < NDB) ? hist[t] : 0;
        if (t < NDB) red[t] = v;
        __syncthreads();
        for (int off = 1; off < NDB; off <<= 1) {
            int a = (t < NDB && t >= off) ? red[t - off] : 0;
            __syncthreads();
            if (t < NDB) red[t] += a;
            __syncthreads();
        }
        if (t < nloc) excl[t] = red[t] - v;
        if (t == 0) excl[nloc] = cnt;
    }
    __syncthreads();
    // ---- rowptr + LDS scatter + ecol flush (for gat2) ----
    if (t < nloc) rowptr[d0 + t] = base + excl[t];
    if (b == NBUCK - 1 && t == 0) rowptr[N_NODES] = base + cnt;
    for (int i = t; i < cnt; i += 512) {
        uint2 pr = eb[i];
        int dl = (int)pr.y - d0;
        int slot = excl[dl] + atomicAdd(&cnt2[dl], 1);
        lds_ecol[slot] = (int)pr.x;
    }
    __syncthreads();
    for (int i = t; i < cnt; i += 512) ecol[base + i] = lds_ecol[i];

    // ---- gat1 phase: 8 waves x wave-strided dsts; edges from LDS ----
    const int wave = t >> 6;
    const int lane = t & 63;
    const int g = lane >> 3;
    const int l = lane & 7;
    for (int di = wave; di < nloc; di += 8) {
        const int dst = d0 + di;
        const int beg = excl[di], end = excl[di + 1];
        const float adh = a1d[(long)dst * 8 + l];

        float acc[8] = {0.f,0.f,0.f,0.f,0.f,0.f,0.f,0.f};
        float den = 0.f;

        int j = beg + g;
        bool v = (j < end);
        int s = v ? lds_ecol[j] : 0;
        unsigned short ab = a1sh[(long)s * 8 + l];
        uint4 pv = *(const uint4*)(h1p + (long)s * 64 + l * 8);

        for (int j0 = beg; j0 < end; j0 += 8) {
            int jn = j + 8;
            bool vn = (jn < end);
            int sn = vn ? lds_ecol[jn] : 0;
            unsigned short abn = a1sh[(long)sn * 8 + l];
            uint4 pvn = *(const uint4*)(h1p + (long)sn * 64 + l * 8);
            float ee = v ? __expf(lrelu(bf2f(ab) + adh)) : 0.f;
            den += ee;
            acc[0] += ee * bflo(pv.x); acc[1] += ee * bfhi(pv.x);
            acc[2] += ee * bflo(pv.y); acc[3] += ee * bfhi(pv.y);
            acc[4] += ee * bflo(pv.z); acc[5] += ee * bfhi(pv.z);
            acc[6] += ee * bflo(pv.w); acc[7] += ee * bfhi(pv.w);
            j = jn; v = vn; s = sn; ab = abn; pv = pvn;
        }
        #pragma unroll
        for (int off = 8; off <= 32; off <<= 1) {
            den += __shfl_xor(den, off, 64);
            #pragma unroll
            for (int k = 0; k < 8; ++k) acc[k] += __shfl_xor(acc[k], off, 64);
        }

        if (g == 0) {
            const float inv = 1.f / den;
            float pg = 0.f, ps = 0.f, pd = 0.f;
            #pragma unroll
            for (int k = 0; k < 8; ++k) {
                float vv = acc[k] * inv + bias1[l * 8 + k];
                vv = vv > 0.f ? vv : (__expf(vv) - 1.f);      // elu -> x2 channel
                pg += vv * wv[l * 8 + k];
                ps += vv * wv[64 + l * 8 + k];
                pd += vv * wv[128 + l * 8 + k];
            }
            #pragma unroll
            for (int off = 1; off < 8; off <<= 1) {
                pg += __shfl_xor(pg, off, 64);
                ps += __shfl_xor(ps, off, 64);
                pd += __shfl_xor(pd, off, 64);
            }
            if (l == 0) { sg2[dst] = make_float2(ps, pg); a2dv[dst] = pd; }
        }
    }
}

// ---- conv2 + pool + linear (persistent, 16-lane subgroups) ---------------
__global__ __launch_bounds__(256) void k_gat2(
    const int* __restrict__ rowptr, const int* __restrict__ ecol,
    const float2* __restrict__ sg2, const float* __restrict__ a2dv,
    const float* __restrict__ wv, const int* __restrict__ batch,
    float* __restrict__ out)
{
    const int lane = threadIdx.x & 63;
    const int sl = lane & 15;
    const int sgid = ((blockIdx.x * 256 + threadIdx.x) >> 4);
    const int NS = G2_BLOCKS * 16;
    const int per = (N_NODES + NS - 1) / NS;
    const int n0 = sgid * per;
    const int n1 = min(n0 + per, N_NODES);
    const float bc = wv[192];

    float accg = 0.f;
    int curg = -1;
    for (int n = n0; n < n1; ++n) {
        const int beg = rowptr[n], end = rowptr[n + 1];
        const float adv = a2dv[n];
        float num = 0.f, den = 0.f;
        for (int j = beg + sl; j < end; j += 16) {
            int s = ecol[j];
            float2 v = sg2[s];
            float ee = __expf(lrelu(v.x + adv));
            den += ee;
            num += ee * v.y;
        }
        #pragma unroll
        for (int off = 1; off < 16; off <<= 1) {
            den += __shfl_xor(den, off, 64);
            num += __shfl_xor(num, off, 64);
        }
        if (sl == 0) {
            int gr = batch[n];
            if (gr != curg) {
                if (curg >= 0) atomAddF(out + curg, accg);
                curg = gr; accg = 0.f;
            }
            accg += num / den + bc;
        }
    }
    if (sl == 0 && curg >= 0) atomAddF(out + curg, accg);
}

extern "C" void kernel_launch(void* const* d_in, const int* in_sizes, int n_in,
                              void* d_out, int out_size, void* d_ws, size_t ws_size,
                              hipStream_t stream) {
    (void)in_sizes; (void)n_in; (void)out_size; (void)ws_size;
    const float* x     = (const float*)d_in[0];
    const int*   ei    = (const int*)d_in[1];
    const int*   batch = (const int*)d_in[2];
    const float* W1    = (const float*)d_in[3];
    const float* as1   = (const float*)d_in[4];
    const float* ad1   = (const float*)d_in[5];
    const float* b1    = (const float*)d_in[6];
    const float* W2    = (const float*)d_in[7];
    const float* as2   = (const float*)d_in[8];
    const float* ad2   = (const float*)d_in[9];
    const float* b2    = (const float*)d_in[10];
    const float* Wg    = (const float*)d_in[11];
    const float* bg    = (const float*)d_in[12];
    float* out = (float*)d_out;

    // ---- workspace layout (16-B aligned chunks; total ~42 MB) ----
    const long N = N_NODES;
    char* p = (char*)d_ws;
    int* rowptr = (int*)p;              p += (N + 4)        * sizeof(int);
    int* bcur   = (int*)p;              p += 1024           * sizeof(int);
    int* ecol   = (int*)p;              p += (long)ET       * sizeof(int);
    uint2* gbuf = (uint2*)p;            p += (long)NBUCK * BCAP * sizeof(uint2);
    unsigned short* h1p  = (unsigned short*)p; p += N * 64  * sizeof(unsigned short);
    unsigned short* a1sh = (unsigned short*)p; p += N * 8   * sizeof(unsigned short);
    float* a1d  = (float*)p;            p += N * 8          * sizeof(float);
    float2* sg2 = (float2*)p;           p += N              * sizeof(float2);
    float* a2dv = (float*)p;            p += N              * sizeof(float);
    float* wv   = (float*)p;            p += 256            * sizeof(float);

    hipMemsetAsync(bcur, 0, NBUCK * sizeof(int), stream);
    // L1: CSR pass A + wv/out-init + conv1 features (co-scheduled)
    k_pre <<<PRE_GRID, 256, 0, stream>>>(ei, gbuf, bcur, x, W1, as1, ad1,
                                         W2, as2, ad2, Wg, b2, bg,
                                         h1p, a1sh, a1d, wv, out);
    // L2: fused CSR pass B + conv1 gather + projection (block = bucket)
    k_gat1<<<NBUCK, 512, 0, stream>>>(gbuf, bcur, rowptr, ecol,
                                      a1sh, a1d, h1p, b1, wv, sg2, a2dv);
    // L3: conv2 + pool + linear (scalar form)
    k_gat2<<<G2_BLOCKS, 256, 0, stream>>>(rowptr, ecol, sg2, a2dv, wv, batch, out);
}